// Round 1
// baseline (3589.656 us; speedup 1.0000x reference)
//
#include <hip/hip_runtime.h>
#include <math.h>

#define VOCAB 20000
#define WORD 620
#define NSEQ 128
#define TMAX 30
#define CTXK 2400
#define XK 3020

typedef unsigned long long u64;

// monotonic float -> uint map (no NaNs expected)
__device__ __forceinline__ unsigned ford(float f) {
    unsigned b = __float_as_uint(f);
    return (b & 0x80000000u) ? ~b : (b | 0x80000000u);
}

// zero last_T (620*128) and slots (30*128)
__global__ __launch_bounds__(256) void kinit(float* last_T, u64* slots) {
    int i = blockIdx.x * 256 + threadIdx.x;
    if (i < WORD * NSEQ) last_T[i] = 0.f;
    if (i < TMAX * NSEQ) slots[i] = 0ull;
}

// ctx_T[k][n] = k<1200 ? thoughts[n][k] : thoughts[n+2][k-1200]
__global__ __launch_bounds__(256) void kctx(const float* __restrict__ th,
                                            float* __restrict__ ctx_T) {
    int i = blockIdx.x * 256 + threadIdx.x;
    if (i >= CTXK * NSEQ) return;
    int n = i & 127;
    int k = i >> 7;
    float v = (k < 1200) ? th[(size_t)n * 1200 + k]
                         : th[(size_t)(n + 2) * 1200 + (k - 1200)];
    ctx_T[(size_t)k * NSEQ + n] = v;
}

// base_T[j][n] = b_ih[j]+b_hh[j] + sum_k ctx_T[k][n] * W_ih[j][k], k<2400
__global__ __launch_bounds__(128) void kbase(const float* __restrict__ W_ih,
                                             const float* __restrict__ b_ih,
                                             const float* __restrict__ b_hh,
                                             const float* __restrict__ ctx_T,
                                             float* __restrict__ base_T) {
    int j = blockIdx.x;    // 0..2479
    int n = threadIdx.x;   // 0..127
    const float* Wr = W_ih + (size_t)j * XK;
    float acc = 0.f;
    for (int k = 0; k < CTXK; k += 4) {
        float4 w4 = *(const float4*)(Wr + k);   // uniform across block
        acc += w4.x * ctx_T[(size_t)(k + 0) * NSEQ + n];
        acc += w4.y * ctx_T[(size_t)(k + 1) * NSEQ + n];
        acc += w4.z * ctx_T[(size_t)(k + 2) * NSEQ + n];
        acc += w4.w * ctx_T[(size_t)(k + 3) * NSEQ + n];
    }
    base_T[(size_t)j * NSEQ + n] = acc + b_ih[j] + b_hh[j];
}

// h_T[w][n] = sigmoid(o)*tanh(sigmoid(i)*tanh(g)); gates = base + last @ Wsub^T
__global__ __launch_bounds__(128) void kgate(const float* __restrict__ W_ih,
                                             const float* __restrict__ base_T,
                                             const float* __restrict__ last_T,
                                             float* __restrict__ h_T) {
    int w = blockIdx.x;    // 0..619
    int n = threadIdx.x;   // 0..127
    const float* Wi = W_ih + (size_t)(0 * WORD + w) * XK + CTXK;  // i-gate row w
    const float* Wg = W_ih + (size_t)(2 * WORD + w) * XK + CTXK;  // g-gate row 1240+w
    const float* Wo = W_ih + (size_t)(3 * WORD + w) * XK + CTXK;  // o-gate row 1860+w
    float ai = 0.f, ag = 0.f, ao = 0.f;
    for (int k = 0; k < WORD; k += 4) {
        float4 wi = *(const float4*)(Wi + k);   // uniform across block
        float4 wg = *(const float4*)(Wg + k);
        float4 wo = *(const float4*)(Wo + k);
        float l0 = last_T[(size_t)(k + 0) * NSEQ + n];
        float l1 = last_T[(size_t)(k + 1) * NSEQ + n];
        float l2 = last_T[(size_t)(k + 2) * NSEQ + n];
        float l3 = last_T[(size_t)(k + 3) * NSEQ + n];
        ai += wi.x * l0 + wi.y * l1 + wi.z * l2 + wi.w * l3;
        ag += wg.x * l0 + wg.y * l1 + wg.z * l2 + wg.w * l3;
        ao += wo.x * l0 + wo.y * l1 + wo.z * l2 + wo.w * l3;
    }
    float gi = ai + base_T[(size_t)(0 * WORD + w) * NSEQ + n];
    float gg = ag + base_T[(size_t)(2 * WORD + w) * NSEQ + n];
    float go = ao + base_T[(size_t)(3 * WORD + w) * NSEQ + n];
    float si = 1.f / (1.f + expf(-gi));
    float so = 1.f / (1.f + expf(-go));
    float c  = si * tanhf(gg);
    float h  = so * tanhf(c);
    h_T[(size_t)w * NSEQ + n] = h;
}

// logits GEMM: C[n][v] = h[n]·Ww[v] + bw[v]; writes out[n][t][v]; argmax via atomicMax
__global__ __launch_bounds__(256) void klogits(const float* __restrict__ Ww,
                                               const float* __restrict__ bw,
                                               const float* __restrict__ h_T,
                                               float* __restrict__ out,
                                               u64* __restrict__ slots, int t) {
    __shared__ float Wl[32][64];   // [k][v]
    __shared__ float Hl[32][64];   // [k][n]
    int tid = threadIdx.x;
    int v0 = blockIdx.x * 64;      // 0..312 tiles
    int n0 = blockIdx.y * 64;      // 0..1
    int tv = tid & 15, tn = tid >> 4;

    float acc[4][4];
#pragma unroll
    for (int i = 0; i < 4; ++i)
#pragma unroll
        for (int j = 0; j < 4; ++j) acc[i][j] = 0.f;

    for (int k0 = 0; k0 < WORD; k0 += 32) {
        __syncthreads();
#pragma unroll
        for (int s = 0; s < 2; ++s) {
            int p = tid + s * 256;          // 0..511
            // --- W tile: 64 rows(v) x 8 float4(k) ---
            int r = p >> 3;                 // v row 0..63
            int c = (p & 7) << 2;           // k col 0,4,..,28
            int v = v0 + r;
            float4 w4 = make_float4(0.f, 0.f, 0.f, 0.f);
            if (v < VOCAB) {
                if (k0 + 32 <= WORD) {
                    w4 = *(const float4*)(Ww + (size_t)v * WORD + k0 + c);
                } else {
                    float e0 = (k0 + c + 0 < WORD) ? Ww[(size_t)v * WORD + k0 + c + 0] : 0.f;
                    float e1 = (k0 + c + 1 < WORD) ? Ww[(size_t)v * WORD + k0 + c + 1] : 0.f;
                    float e2 = (k0 + c + 2 < WORD) ? Ww[(size_t)v * WORD + k0 + c + 2] : 0.f;
                    float e3 = (k0 + c + 3 < WORD) ? Ww[(size_t)v * WORD + k0 + c + 3] : 0.f;
                    w4 = make_float4(e0, e1, e2, e3);
                }
            }
            Wl[c + 0][r] = w4.x; Wl[c + 1][r] = w4.y;
            Wl[c + 2][r] = w4.z; Wl[c + 3][r] = w4.w;
            // --- H tile: 32 rows(k) x 16 float4(n) --- (h_T already [k][n])
            int kk = p >> 4;                // 0..31
            int q = (p & 15) << 2;          // n col
            float4 h4 = make_float4(0.f, 0.f, 0.f, 0.f);
            if (k0 + kk < WORD)
                h4 = *(const float4*)(h_T + (size_t)(k0 + kk) * NSEQ + n0 + q);
            *(float4*)&Hl[kk][q] = h4;
        }
        __syncthreads();
#pragma unroll
        for (int kk = 0; kk < 32; ++kk) {
            float4 w4 = *(const float4*)&Wl[kk][tv << 2];
            float4 h4 = *(const float4*)&Hl[kk][tn << 2];
            acc[0][0] += h4.x * w4.x; acc[0][1] += h4.x * w4.y;
            acc[0][2] += h4.x * w4.z; acc[0][3] += h4.x * w4.w;
            acc[1][0] += h4.y * w4.x; acc[1][1] += h4.y * w4.y;
            acc[1][2] += h4.y * w4.z; acc[1][3] += h4.y * w4.w;
            acc[2][0] += h4.z * w4.x; acc[2][1] += h4.z * w4.y;
            acc[2][2] += h4.z * w4.z; acc[2][3] += h4.z * w4.w;
            acc[3][0] += h4.w * w4.x; acc[3][1] += h4.w * w4.y;
            acc[3][2] += h4.w * w4.z; acc[3][3] += h4.w * w4.w;
        }
    }

    int bv = v0 + (tv << 2);
    float4 bw4 = make_float4(0.f, 0.f, 0.f, 0.f);
    if (bv < VOCAB) bw4 = *(const float4*)(bw + bv);   // VOCAB%4==0: row fully in or out
#pragma unroll
    for (int i = 0; i < 4; ++i) {
        int n = n0 + (tn << 2) + i;
        u64 key = 0ull;
        if (bv < VOCAB) {
            float r0 = acc[i][0] + bw4.x, r1 = acc[i][1] + bw4.y;
            float r2 = acc[i][2] + bw4.z, r3 = acc[i][3] + bw4.w;
            size_t ob = ((size_t)n * TMAX + t) * VOCAB + bv;
            *(float4*)(out + ob) = make_float4(r0, r1, r2, r3);
            float best = r0; int bj = 0;
            if (r1 > best) { best = r1; bj = 1; }
            if (r2 > best) { best = r2; bj = 2; }
            if (r3 > best) { best = r3; bj = 3; }
            key = ((u64)ford(best) << 32) |
                  (u64)(unsigned)(0xFFFFFFFFu - (unsigned)(bv + bj));
        }
#pragma unroll
        for (int m = 1; m <= 8; m <<= 1) {
            u64 o = __shfl_xor(key, m, 64);
            if (o > key) key = o;
        }
        if (tv == 0) atomicMax(&slots[t * NSEQ + n], key);
    }
}

// last_T[k][n] = embed[argmax_idx[n]][k]
__global__ __launch_bounds__(128) void kgather(const float* __restrict__ embed,
                                               const u64* __restrict__ slots,
                                               float* __restrict__ last_T, int t) {
    int k = blockIdx.x;    // 0..619
    int n = threadIdx.x;   // 0..127
    u64 s = slots[t * NSEQ + n];
    unsigned idx = 0xFFFFFFFFu - (unsigned)(s & 0xFFFFFFFFull);
    last_T[(size_t)k * NSEQ + n] = embed[(size_t)idx * WORD + k];
}

extern "C" void kernel_launch(void* const* d_in, const int* in_sizes, int n_in,
                              void* d_out, int out_size, void* d_ws, size_t ws_size,
                              hipStream_t stream) {
    const float* thoughts = (const float*)d_in[0];
    const float* embed    = (const float*)d_in[1];
    const float* W_ih     = (const float*)d_in[2];
    // d_in[3] = W_hh: dead (h0 == 0 always)
    const float* b_ih     = (const float*)d_in[4];
    const float* b_hh     = (const float*)d_in[5];
    const float* Ww       = (const float*)d_in[6];
    const float* bw       = (const float*)d_in[7];
    float* out = (float*)d_out;

    char* ws = (char*)d_ws;
    float* ctx_T  = (float*)(ws + 0);         // 2400*128 f32 = 1,228,800 B
    float* base_T = (float*)(ws + 1228800);   // 2480*128 f32 = 1,269,760 B
    float* last_T = (float*)(ws + 2498560);   //  620*128 f32 =   317,440 B
    float* h_T    = (float*)(ws + 2816000);   //  620*128 f32 =   317,440 B
    u64*   slots  = (u64*)  (ws + 3133440);   //   30*128 u64 =    30,720 B

    kinit<<<310, 256, 0, stream>>>(last_T, slots);
    kctx<<<1200, 256, 0, stream>>>(thoughts, ctx_T);
    kbase<<<2480, 128, 0, stream>>>(W_ih, b_ih, b_hh, ctx_T, base_T);

    for (int t = 0; t < TMAX; ++t) {
        kgate<<<620, 128, 0, stream>>>(W_ih, base_T, last_T, h_T);
        klogits<<<dim3(313, 2), 256, 0, stream>>>(Ww, bw, h_T, out, slots, t);
        if (t + 1 < TMAX)
            kgather<<<620, 128, 0, stream>>>(embed, slots, last_T, t);
    }
}

// Round 2
// 2781.496 us; speedup vs baseline: 1.2905x; 1.2905x over previous
//
#include <hip/hip_runtime.h>
#include <math.h>

#define VOCAB 20000
#define WORD 620
#define NSEQ 128
#define TMAX 30
#define CTXK 2400
#define XK 3020

typedef unsigned long long u64;
typedef __attribute__((ext_vector_type(8))) short short8;
typedef __attribute__((ext_vector_type(4))) float f32x4;

// ---------- helpers ----------
__device__ __forceinline__ unsigned ford(float f) {
    unsigned b = __float_as_uint(f);
    return (b & 0x80000000u) ? ~b : (b | 0x80000000u);
}
__device__ __forceinline__ unsigned short bf16rne(float x) {
    unsigned u = __float_as_uint(x);
    return (unsigned short)((u + 0x7fffu + ((u >> 16) & 1u)) >> 16);
}
__device__ __forceinline__ float bf16tof(unsigned short h) {
    return __uint_as_float(((unsigned)h) << 16);
}
__device__ __forceinline__ short8 ld8(const unsigned short* p) {
    return *(const short8*)p;
}
#define MFMA(a, b, c) __builtin_amdgcn_mfma_f32_16x16x32_bf16((a), (b), (c), 0, 0, 0)

// =====================================================================
// MFMA split-bf16 path
// Fragment order (m91-verified trio):
//   A frag: lane holds A[row = mt*16 + lane%16][k = ks*32 + (lane/16)*8 + j]
//   B frag: lane holds B[col = vt*16 + lane%16][k = ks*32 + (lane/16)*8 + j]
//   C/D:    row = (lane>>4)*4 + r, col = lane&15
// Buffers: Afrag [ks][mt][s][64][8] shorts;  Bfrag [vt][ks][s][64][8] shorts
// =====================================================================

// zero lastfrag+hfrag (incl. k-pad), slots; build bsum
__global__ __launch_bounds__(256) void kinit2(unsigned int* lastfrag32,
                                              unsigned int* hfrag32,
                                              unsigned int* slots32,
                                              float* bsum,
                                              const float* __restrict__ b_ih,
                                              const float* __restrict__ b_hh) {
    int i = blockIdx.x * 256 + threadIdx.x;
    if (i < 81920) { lastfrag32[i] = 0u; hfrag32[i] = 0u; }
    if (i < 7680) slots32[i] = 0u;
    if (i < 1872) {
        float v = 0.f;
        if (i < 1860) {
            int row = (i < 620) ? i : i + 620;   // [i, g, o] -> W_ih rows
            v = b_ih[row] + b_hh[row];
        }
        bsum[i] = v;
    }
}

// pack W-style matrix [rows][src_ld] f32 -> frag [vt][ks][2][64][8]
// rowmap: 0 = direct row, 1 = gate mapping (j<620 -> j, else j+620)
__global__ __launch_bounds__(256) void kpack_w(const float* __restrict__ src,
                                               unsigned short* __restrict__ dst,
                                               int nvt, int nks, int col0,
                                               int ncols_valid, int src_ld,
                                               int nrows_valid, int rowmap) {
    int i = blockIdx.x * 256 + threadIdx.x;
    if (i >= nvt * nks * 512) return;
    int j = i & 7;
    int lane = (i >> 3) & 63;
    int t2 = i >> 9;                    // vt*nks + ks
    int ks = t2 % nks;
    int vt = t2 / nks;
    int r = vt * 16 + (lane & 15);
    int k = ks * 32 + ((lane >> 4) << 3) + j;
    float x = 0.f;
    if (r < nrows_valid && k < ncols_valid) {
        int row = (rowmap == 1) ? ((r < 620) ? r : r + 620) : r;
        x = src[(size_t)row * src_ld + col0 + k];
    }
    unsigned short hi = bf16rne(x);
    unsigned short lo = bf16rne(x - bf16tof(hi));
    size_t ob = (size_t)t2 * 1024 + lane * 8 + j;
    dst[ob] = hi;
    dst[ob + 512] = lo;
}

// pack ctx (concat of thoughts[:-2], thoughts[2:]) -> A-frag [ks][mt][2][64][8]
__global__ __launch_bounds__(256) void kpack_ctx(const float* __restrict__ th,
                                                 unsigned short* __restrict__ dst) {
    int i = blockIdx.x * 256 + threadIdx.x;
    if (i >= 75 * 8 * 512) return;
    int j = i & 7;
    int lane = (i >> 3) & 63;
    int t2 = i >> 9;                    // ks*8 + mt
    int mt = t2 & 7;
    int ks = t2 >> 3;
    int n = mt * 16 + (lane & 15);
    int k = ks * 32 + ((lane >> 4) << 3) + j;
    float x = (k < 1200) ? th[(size_t)n * 1200 + k]
                         : th[(size_t)(n + 2) * 1200 + (k - 1200)];
    unsigned short hi = bf16rne(x);
    unsigned short lo = bf16rne(x - bf16tof(hi));
    size_t ob = (size_t)t2 * 1024 + lane * 8 + j;
    dst[ob] = hi;
    dst[ob + 512] = lo;
}

// generic frag GEMM: outT[row][col] (row<128, col<nvt*16) = A@B^T (+addRow[col]) (+addFull[row][col])
__global__ __launch_bounds__(256) void ggemm(const unsigned short* __restrict__ Af,
                                             const unsigned short* __restrict__ Bf,
                                             const float* __restrict__ addRow,
                                             const float* __restrict__ addFull,
                                             float* __restrict__ outT,
                                             int nks, int nvt, int ldout) {
    int lane = threadIdx.x & 63, wv = threadIdx.x >> 6;
    int vtb = blockIdx.x * 8 + wv * 2;
    bool ok0 = vtb < nvt, ok1 = (vtb + 1) < nvt;
    f32x4 acc[8][2];
#pragma unroll
    for (int m = 0; m < 8; ++m) { acc[m][0] = (f32x4)0.f; acc[m][1] = (f32x4)0.f; }

    if (ok0) {
        const unsigned short* ap = Af + lane * 8;
        const unsigned short* bp0 = Bf + (size_t)vtb * nks * 1024 + lane * 8;
        const unsigned short* bp1 = bp0 + (size_t)nks * 1024;
        for (int ks = 0; ks < nks; ++ks) {
            short8 b0h = ld8(bp0), b0l = ld8(bp0 + 512);
            short8 ah[8], al[8];
#pragma unroll
            for (int m = 0; m < 8; ++m) {
                ah[m] = ld8(ap + m * 1024);
                al[m] = ld8(ap + m * 1024 + 512);
            }
#pragma unroll
            for (int m = 0; m < 8; ++m) {
                acc[m][0] = MFMA(ah[m], b0h, acc[m][0]);
                acc[m][0] = MFMA(ah[m], b0l, acc[m][0]);
                acc[m][0] = MFMA(al[m], b0h, acc[m][0]);
            }
            if (ok1) {
                short8 b1h = ld8(bp1), b1l = ld8(bp1 + 512);
#pragma unroll
                for (int m = 0; m < 8; ++m) {
                    acc[m][1] = MFMA(ah[m], b1h, acc[m][1]);
                    acc[m][1] = MFMA(ah[m], b1l, acc[m][1]);
                    acc[m][1] = MFMA(al[m], b1h, acc[m][1]);
                }
            }
            ap += 8192; bp0 += 1024; bp1 += 1024;
        }
    }
    int rbase = (lane >> 4) << 2;
    int cof = lane & 15;
#pragma unroll
    for (int v = 0; v < 2; ++v) {
        bool ok = v ? ok1 : ok0;
        if (!ok) continue;
        int col = (vtb + v) * 16 + cof;
        float ar = addRow ? addRow[col] : 0.f;
#pragma unroll
        for (int m = 0; m < 8; ++m) {
#pragma unroll
            for (int r = 0; r < 4; ++r) {
                int row = m * 16 + rbase + r;
                float x = acc[m][v][r] + ar;
                if (addFull) x += addFull[(size_t)row * ldout + col];
                outT[(size_t)row * ldout + col] = x;
            }
        }
    }
}

// logits GEMM + bias + store + argmax (block-reduced, then global atomicMax)
__global__ __launch_bounds__(256) void klogits2(const unsigned short* __restrict__ Hf,
                                                const unsigned short* __restrict__ Wf,
                                                const float* __restrict__ bw,
                                                float* __restrict__ out,
                                                u64* __restrict__ slots, int t) {
    __shared__ u64 keybuf[128];
    int tid = threadIdx.x;
    if (tid < 128) keybuf[tid] = 0ull;
    __syncthreads();
    int lane = tid & 63, wv = tid >> 6;
    int vtb = blockIdx.x * 8 + wv * 2;
    bool ok0 = vtb < 1250, ok1 = (vtb + 1) < 1250;
    f32x4 acc[8][2];
#pragma unroll
    for (int m = 0; m < 8; ++m) { acc[m][0] = (f32x4)0.f; acc[m][1] = (f32x4)0.f; }

    if (ok0) {
        const unsigned short* ap = Hf + lane * 8;
        const unsigned short* bp0 = Wf + (size_t)vtb * 20 * 1024 + lane * 8;
        const unsigned short* bp1 = bp0 + 20 * 1024;
#pragma unroll 2
        for (int ks = 0; ks < 20; ++ks) {
            short8 b0h = ld8(bp0), b0l = ld8(bp0 + 512);
            short8 ah[8], al[8];
#pragma unroll
            for (int m = 0; m < 8; ++m) {
                ah[m] = ld8(ap + m * 1024);
                al[m] = ld8(ap + m * 1024 + 512);
            }
#pragma unroll
            for (int m = 0; m < 8; ++m) {
                acc[m][0] = MFMA(ah[m], b0h, acc[m][0]);
                acc[m][0] = MFMA(ah[m], b0l, acc[m][0]);
                acc[m][0] = MFMA(al[m], b0h, acc[m][0]);
            }
            if (ok1) {
                short8 b1h = ld8(bp1), b1l = ld8(bp1 + 512);
#pragma unroll
                for (int m = 0; m < 8; ++m) {
                    acc[m][1] = MFMA(ah[m], b1h, acc[m][1]);
                    acc[m][1] = MFMA(ah[m], b1l, acc[m][1]);
                    acc[m][1] = MFMA(al[m], b1h, acc[m][1]);
                }
            }
            ap += 8192; bp0 += 1024; bp1 += 1024;
        }
    }
    int rbase = (lane >> 4) << 2;
    int cof = lane & 15;
    float bw0 = ok0 ? bw[vtb * 16 + cof] : 0.f;
    float bw1 = ok1 ? bw[(vtb + 1) * 16 + cof] : 0.f;
#pragma unroll
    for (int m = 0; m < 8; ++m) {
#pragma unroll
        for (int r = 0; r < 4; ++r) {
            int row = m * 16 + rbase + r;
            u64 km = 0ull;
            if (ok0) {
                int v = vtb * 16 + cof;
                float x = acc[m][0][r] + bw0;
                out[((size_t)row * TMAX + t) * VOCAB + v] = x;
                km = ((u64)ford(x) << 32) | (u64)(0xFFFFFFFFu - (unsigned)v);
            }
            if (ok1) {
                int v = (vtb + 1) * 16 + cof;
                float x = acc[m][1][r] + bw1;
                out[((size_t)row * TMAX + t) * VOCAB + v] = x;
                u64 k2 = ((u64)ford(x) << 32) | (u64)(0xFFFFFFFFu - (unsigned)v);
                if (k2 > km) km = k2;
            }
#pragma unroll
            for (int s2 = 1; s2 <= 8; s2 <<= 1) {
                u64 o = __shfl_xor(km, s2, 64);
                if (o > km) km = o;
            }
            if ((lane & 15) == 0 && km) atomicMax(&keybuf[row], km);
        }
    }
    __syncthreads();
    if (tid < 128) atomicMax(&slots[(size_t)t * NSEQ + tid], keybuf[tid]);
}

// activation: gates[128][1872] -> h -> hfrag (hi/lo, frag order)
__global__ void kact(const float* __restrict__ gates,
                     unsigned short* __restrict__ hfrag) {
    int n = blockIdx.x;
    int k = threadIdx.x;
    if (k >= WORD) return;
    const float* g = gates + (size_t)n * 1872;
    float gi = g[k], gg = g[620 + k], go = g[1240 + k];
    float si = 1.f / (1.f + expf(-gi));
    float so = 1.f / (1.f + expf(-go));
    float h = so * tanhf(si * tanhf(gg));
    int ks = k >> 5, mt = n >> 4;
    int lane = (n & 15) + (((k & 31) >> 3) << 4);
    int j = k & 7;
    size_t ob = (size_t)(ks * 8 + mt) * 1024 + lane * 8 + j;
    unsigned short hi = bf16rne(h);
    hfrag[ob] = hi;
    hfrag[ob + 512] = bf16rne(h - bf16tof(hi));
}

// gather decoded word embedding -> lastfrag (hi/lo, frag order)
__global__ void kgather2(const float* __restrict__ embed,
                         const u64* __restrict__ slots,
                         unsigned short* __restrict__ lastfrag, int t) {
    int n = blockIdx.x;
    int k = threadIdx.x;
    if (k >= WORD) return;
    u64 s = slots[(size_t)t * NSEQ + n];
    unsigned idx = 0xFFFFFFFFu - (unsigned)(s & 0xFFFFFFFFull);
    float x = embed[(size_t)idx * WORD + k];
    int ks = k >> 5, mt = n >> 4;
    int lane = (n & 15) + (((k & 31) >> 3) << 4);
    int j = k & 7;
    size_t ob = (size_t)(ks * 8 + mt) * 1024 + lane * 8 + j;
    unsigned short hi = bf16rne(x);
    lastfrag[ob] = hi;
    lastfrag[ob + 512] = bf16rne(x - bf16tof(hi));
}

// =====================================================================
// fallback f32 path (round-1, passes; used only if ws too small)
// =====================================================================
__global__ __launch_bounds__(256) void kinit_o(float* last_T, u64* slots) {
    int i = blockIdx.x * 256 + threadIdx.x;
    if (i < WORD * NSEQ) last_T[i] = 0.f;
    if (i < TMAX * NSEQ) slots[i] = 0ull;
}
__global__ __launch_bounds__(256) void kctx_o(const float* __restrict__ th,
                                              float* __restrict__ ctx_T) {
    int i = blockIdx.x * 256 + threadIdx.x;
    if (i >= CTXK * NSEQ) return;
    int n = i & 127, k = i >> 7;
    float v = (k < 1200) ? th[(size_t)n * 1200 + k]
                         : th[(size_t)(n + 2) * 1200 + (k - 1200)];
    ctx_T[(size_t)k * NSEQ + n] = v;
}
__global__ __launch_bounds__(128) void kbase_o(const float* __restrict__ W_ih,
                                               const float* __restrict__ b_ih,
                                               const float* __restrict__ b_hh,
                                               const float* __restrict__ ctx_T,
                                               float* __restrict__ base_T) {
    int j = blockIdx.x, n = threadIdx.x;
    const float* Wr = W_ih + (size_t)j * XK;
    float acc = 0.f;
    for (int k = 0; k < CTXK; k += 4) {
        float4 w4 = *(const float4*)(Wr + k);
        acc += w4.x * ctx_T[(size_t)(k + 0) * NSEQ + n];
        acc += w4.y * ctx_T[(size_t)(k + 1) * NSEQ + n];
        acc += w4.z * ctx_T[(size_t)(k + 2) * NSEQ + n];
        acc += w4.w * ctx_T[(size_t)(k + 3) * NSEQ + n];
    }
    base_T[(size_t)j * NSEQ + n] = acc + b_ih[j] + b_hh[j];
}
__global__ __launch_bounds__(128) void kgate_o(const float* __restrict__ W_ih,
                                               const float* __restrict__ base_T,
                                               const float* __restrict__ last_T,
                                               float* __restrict__ h_T) {
    int w = blockIdx.x, n = threadIdx.x;
    const float* Wi = W_ih + (size_t)(0 * WORD + w) * XK + CTXK;
    const float* Wg = W_ih + (size_t)(2 * WORD + w) * XK + CTXK;
    const float* Wo = W_ih + (size_t)(3 * WORD + w) * XK + CTXK;
    float ai = 0.f, ag = 0.f, ao = 0.f;
    for (int k = 0; k < WORD; k += 4) {
        float4 wi = *(const float4*)(Wi + k);
        float4 wg = *(const float4*)(Wg + k);
        float4 wo = *(const float4*)(Wo + k);
        float l0 = last_T[(size_t)(k + 0) * NSEQ + n];
        float l1 = last_T[(size_t)(k + 1) * NSEQ + n];
        float l2 = last_T[(size_t)(k + 2) * NSEQ + n];
        float l3 = last_T[(size_t)(k + 3) * NSEQ + n];
        ai += wi.x * l0 + wi.y * l1 + wi.z * l2 + wi.w * l3;
        ag += wg.x * l0 + wg.y * l1 + wg.z * l2 + wg.w * l3;
        ao += wo.x * l0 + wo.y * l1 + wo.z * l2 + wo.w * l3;
    }
    float gi = ai + base_T[(size_t)(0 * WORD + w) * NSEQ + n];
    float gg = ag + base_T[(size_t)(2 * WORD + w) * NSEQ + n];
    float go = ao + base_T[(size_t)(3 * WORD + w) * NSEQ + n];
    float si = 1.f / (1.f + expf(-gi));
    float so = 1.f / (1.f + expf(-go));
    h_T[(size_t)w * NSEQ + n] = so * tanhf(si * tanhf(gg));
}
__global__ __launch_bounds__(256) void klogits_o(const float* __restrict__ Ww,
                                                 const float* __restrict__ bw,
                                                 const float* __restrict__ h_T,
                                                 float* __restrict__ out,
                                                 u64* __restrict__ slots, int t) {
    __shared__ float Wl[32][64];
    __shared__ float Hl[32][64];
    int tid = threadIdx.x;
    int v0 = blockIdx.x * 64, n0 = blockIdx.y * 64;
    int tv = tid & 15, tn = tid >> 4;
    float acc[4][4];
#pragma unroll
    for (int i = 0; i < 4; ++i)
#pragma unroll
        for (int j = 0; j < 4; ++j) acc[i][j] = 0.f;
    for (int k0 = 0; k0 < WORD; k0 += 32) {
        __syncthreads();
#pragma unroll
        for (int s = 0; s < 2; ++s) {
            int p = tid + s * 256;
            int r = p >> 3, c = (p & 7) << 2;
            int v = v0 + r;
            float4 w4 = make_float4(0.f, 0.f, 0.f, 0.f);
            if (v < VOCAB) {
                if (k0 + 32 <= WORD) {
                    w4 = *(const float4*)(Ww + (size_t)v * WORD + k0 + c);
                } else {
                    float e0 = (k0 + c + 0 < WORD) ? Ww[(size_t)v * WORD + k0 + c + 0] : 0.f;
                    float e1 = (k0 + c + 1 < WORD) ? Ww[(size_t)v * WORD + k0 + c + 1] : 0.f;
                    float e2 = (k0 + c + 2 < WORD) ? Ww[(size_t)v * WORD + k0 + c + 2] : 0.f;
                    float e3 = (k0 + c + 3 < WORD) ? Ww[(size_t)v * WORD + k0 + c + 3] : 0.f;
                    w4 = make_float4(e0, e1, e2, e3);
                }
            }
            Wl[c + 0][r] = w4.x; Wl[c + 1][r] = w4.y;
            Wl[c + 2][r] = w4.z; Wl[c + 3][r] = w4.w;
            int kk = p >> 4, q = (p & 15) << 2;
            float4 h4 = make_float4(0.f, 0.f, 0.f, 0.f);
            if (k0 + kk < WORD)
                h4 = *(const float4*)(h_T + (size_t)(k0 + kk) * NSEQ + n0 + q);
            *(float4*)&Hl[kk][q] = h4;
        }
        __syncthreads();
#pragma unroll
        for (int kk = 0; kk < 32; ++kk) {
            float4 w4 = *(const float4*)&Wl[kk][tv << 2];
            float4 h4 = *(const float4*)&Hl[kk][tn << 2];
            acc[0][0] += h4.x * w4.x; acc[0][1] += h4.x * w4.y;
            acc[0][2] += h4.x * w4.z; acc[0][3] += h4.x * w4.w;
            acc[1][0] += h4.y * w4.x; acc[1][1] += h4.y * w4.y;
            acc[1][2] += h4.y * w4.z; acc[1][3] += h4.y * w4.w;
            acc[2][0] += h4.z * w4.x; acc[2][1] += h4.z * w4.y;
            acc[2][2] += h4.z * w4.z; acc[2][3] += h4.z * w4.w;
            acc[3][0] += h4.w * w4.x; acc[3][1] += h4.w * w4.y;
            acc[3][2] += h4.w * w4.z; acc[3][3] += h4.w * w4.w;
        }
    }
    int bv = v0 + (tv << 2);
    float4 bw4 = make_float4(0.f, 0.f, 0.f, 0.f);
    if (bv < VOCAB) bw4 = *(const float4*)(bw + bv);
#pragma unroll
    for (int i = 0; i < 4; ++i) {
        int n = n0 + (tn << 2) + i;
        u64 key = 0ull;
        if (bv < VOCAB) {
            float r0 = acc[i][0] + bw4.x, r1 = acc[i][1] + bw4.y;
            float r2 = acc[i][2] + bw4.z, r3 = acc[i][3] + bw4.w;
            size_t ob = ((size_t)n * TMAX + t) * VOCAB + bv;
            *(float4*)(out + ob) = make_float4(r0, r1, r2, r3);
            float best = r0; int bj = 0;
            if (r1 > best) { best = r1; bj = 1; }
            if (r2 > best) { best = r2; bj = 2; }
            if (r3 > best) { best = r3; bj = 3; }
            key = ((u64)ford(best) << 32) |
                  (u64)(unsigned)(0xFFFFFFFFu - (unsigned)(bv + bj));
        }
#pragma unroll
        for (int m = 1; m <= 8; m <<= 1) {
            u64 o = __shfl_xor(key, m, 64);
            if (o > key) key = o;
        }
        if (tv == 0) atomicMax(&slots[t * NSEQ + n], key);
    }
}
__global__ __launch_bounds__(128) void kgather_o(const float* __restrict__ embed,
                                                 const u64* __restrict__ slots,
                                                 float* __restrict__ last_T, int t) {
    int k = blockIdx.x, n = threadIdx.x;
    u64 s = slots[t * NSEQ + n];
    unsigned idx = 0xFFFFFFFFu - (unsigned)(s & 0xFFFFFFFFull);
    last_T[(size_t)k * NSEQ + n] = embed[(size_t)idx * WORD + k];
}

// =====================================================================
extern "C" void kernel_launch(void* const* d_in, const int* in_sizes, int n_in,
                              void* d_out, int out_size, void* d_ws, size_t ws_size,
                              hipStream_t stream) {
    const float* thoughts = (const float*)d_in[0];
    const float* embed    = (const float*)d_in[1];
    const float* W_ih     = (const float*)d_in[2];
    // d_in[3] = W_hh: dead (h0 == 0 always)
    const float* b_ih     = (const float*)d_in[4];
    const float* b_hh     = (const float*)d_in[5];
    const float* Ww       = (const float*)d_in[6];
    const float* bw       = (const float*)d_in[7];
    float* out = (float*)d_out;
    char* ws = (char*)d_ws;

    const size_t OFF_WWF  = 0;                       // 51,200,000
    const size_t OFF_WBF  = 51200000;                // 17,971,200
    const size_t OFF_WGF  = 69171200;                //  4,792,320
    const size_t OFF_CTXF = 73963520;                //  1,228,800
    const size_t OFF_HF   = 75192320;                //    327,680
    const size_t OFF_LF   = 75520000;                //    327,680
    const size_t OFF_BASE = 75847680;                //    958,464
    const size_t OFF_GATE = 76806144;                //    958,464
    const size_t OFF_BSUM = 77764608;                //      7,488
    const size_t OFF_SLOT = 77772096;                //     30,720
    const size_t NEED = 77802816;

    if (ws_size >= NEED) {
        unsigned short* Wwf  = (unsigned short*)(ws + OFF_WWF);
        unsigned short* Wbf  = (unsigned short*)(ws + OFF_WBF);
        unsigned short* Wgf  = (unsigned short*)(ws + OFF_WGF);
        unsigned short* ctxf = (unsigned short*)(ws + OFF_CTXF);
        unsigned short* hf   = (unsigned short*)(ws + OFF_HF);
        unsigned short* lf   = (unsigned short*)(ws + OFF_LF);
        float* base = (float*)(ws + OFF_BASE);
        float* gate = (float*)(ws + OFF_GATE);
        float* bsum = (float*)(ws + OFF_BSUM);
        u64*   slots = (u64*)(ws + OFF_SLOT);

        kinit2<<<320, 256, 0, stream>>>((unsigned int*)lf, (unsigned int*)hf,
                                        (unsigned int*)slots, bsum, b_ih, b_hh);
        // Ww: 1250 vtiles x 20 ks, rows=20000, cols 0..619 of ld 620
        kpack_w<<<(1250 * 20 * 512 + 255) / 256, 256, 0, stream>>>(
            Ww, Wwf, 1250, 20, 0, 620, WORD, VOCAB, 0);
        // W_ih ctx part: 117 vtiles x 75 ks, gate-mapped 1860 rows, cols 0..2399
        kpack_w<<<(117 * 75 * 512 + 255) / 256, 256, 0, stream>>>(
            W_ih, Wbf, 117, 75, 0, 2400, XK, 1860, 1);
        // W_ih last-word part: 117 vtiles x 20 ks, cols 2400..3019
        kpack_w<<<(117 * 20 * 512 + 255) / 256, 256, 0, stream>>>(
            W_ih, Wgf, 117, 20, 2400, 620, XK, 1860, 1);
        kpack_ctx<<<(75 * 8 * 512 + 255) / 256, 256, 0, stream>>>(thoughts, ctxf);

        // base[n][j] = ctx @ Wb^T + (b_ih+b_hh)
        ggemm<<<15, 256, 0, stream>>>(ctxf, Wbf, bsum, nullptr, base, 75, 117, 1872);

        for (int t = 0; t < TMAX; ++t) {
            // gates[n][j] = last @ Wg^T + base
            ggemm<<<15, 256, 0, stream>>>(lf, Wgf, nullptr, base, gate, 20, 117, 1872);
            kact<<<NSEQ, 640, 0, stream>>>(gate, hf);
            klogits2<<<157, 256, 0, stream>>>(hf, Wwf, bw, out, slots, t);
            if (t + 1 < TMAX)
                kgather2<<<NSEQ, 640, 0, stream>>>(embed, slots, lf, t);
        }
    } else {
        // fallback: round-1 f32 path (needs ~3.2 MB ws)
        float* ctx_T  = (float*)(ws + 0);
        float* base_T = (float*)(ws + 1228800);
        float* last_T = (float*)(ws + 2498560);
        float* h_T    = (float*)(ws + 2816000);
        u64*   slots  = (u64*)  (ws + 3133440);

        kinit_o<<<310, 256, 0, stream>>>(last_T, slots);
        kctx_o<<<1200, 256, 0, stream>>>(thoughts, ctx_T);
        kbase_o<<<2480, 128, 0, stream>>>(W_ih, b_ih, b_hh, ctx_T, base_T);
        for (int t = 0; t < TMAX; ++t) {
            kgate_o<<<620, 128, 0, stream>>>(W_ih, base_T, last_T, h_T);
            klogits_o<<<dim3(313, 2), 256, 0, stream>>>(Ww, bw, h_T, out, slots, t);
            if (t + 1 < TMAX)
                kgather_o<<<620, 128, 0, stream>>>(embed, slots, last_T, t);
        }
    }
}